// Round 4
// baseline (210.247 us; speedup 1.0000x reference)
//
#include <hip/hip_runtime.h>
#include <stdint.h>
#include <math.h>

// Problem constants
#define NPTS 32768
#define PP   5
#define MM   1024
#define JJ   24
#define HH   256

// out (f32 element offsets), total 2,293,760 floats
#define O0 0                // tpose        [1,N,P,3]
#define O1 491520           // tpose_dirs   [1,N,P,3]
#define O2 983040           // resd         [1,N,P,3]
#define O3 1474560          // pflag        [1,N,P]
#define O4 1638400          // init_bigpose [1,N*P,3]
#define O5 2129920          // pnorm        [1,N*P]

typedef unsigned short ushort_t;
typedef unsigned int   uint_t;
typedef unsigned long long u64_t;
typedef __attribute__((ext_vector_type(8))) short bf16x8;
typedef __attribute__((ext_vector_type(4))) float f32x4;

__device__ __forceinline__ ushort_t f2bf(float f) {
  union { uint_t i; float f; } v; v.f = f;
  uint_t i = v.i;
  return (ushort_t)((i + 0x7FFFu + ((i >> 16) & 1u)) >> 16);  // RNE
}
// hardware packed f32->bf16 (RNE, bit-identical to f2bf for finite values)
__device__ __forceinline__ uint_t cvt_pk_bf16(float lo, float hi) {
  uint_t r;
  asm("v_cvt_pk_bf16_f32 %0, %1, %2" : "=v"(r) : "v"(lo), "v"(hi));
  return r;
}
__device__ __forceinline__ float tanh_fast(float v) {
  v = fminf(fmaxf(v, -15.f), 15.f);
  float e = __expf(2.f*v);               // v_exp_f32 path
  return __fdividef(e - 1.f, e + 1.f);   // abs err < 1e-6, plenty for tolerance
}

// ---------------- prep: W2 f32 -> bf16 in MFMA B-fragment order ----------------
// idx = kc*8192 + tile*512 + lane*8 + j  (lane=quad*16+(n&15), quad=(k&31)>>3, j=k&7)
__global__ __launch_bounds__(256) void prep_w2(const float* __restrict__ W2g,
                                               ushort_t* __restrict__ W2bf)
{
  int k = blockIdx.x;
  int n = threadIdx.x;
  float v = W2g[k*256 + n];
  int kc = k >> 5, quad = (k & 31) >> 3, j = k & 7;
  int tile = n >> 4, lane = quad*16 + (n & 15);
  W2bf[kc*8192 + tile*512 + lane*8 + j] = f2bf(v);
}

// ---------------- LBS transform for one (n,p) row ----------------
__device__ __forceinline__ void transform_one(
    int n, int p, int nn, float pn, float fl,
    float px, float py, float pz, float dx, float dy, float dz,
    const float* __restrict__ pbw,
    const float4* __restrict__ sA4, const float4* __restrict__ sB4,
    float* __restrict__ out)
{
  const float4* bwr = (const float4*)(pbw + ((size_t)p * MM + nn) * JJ);
  float bw[24];
  #pragma unroll
  for (int q = 0; q < 6; ++q) {
    float4 u = bwr[q];
    bw[q*4+0] = u.x; bw[q*4+1] = u.y; bw[q*4+2] = u.z; bw[q*4+3] = u.w;
  }

  float M1[12], M2[12];
  #pragma unroll
  for (int q = 0; q < 12; ++q) { M1[q] = 0.f; M2[q] = 0.f; }
  #pragma unroll
  for (int j = 0; j < 24; ++j) {
    float w = bw[j];
    float4 a0 = sA4[j*3+0], a1 = sA4[j*3+1], a2 = sA4[j*3+2];
    M1[0]=fmaf(w,a0.x,M1[0]); M1[1]=fmaf(w,a0.y,M1[1]); M1[2]=fmaf(w,a0.z,M1[2]); M1[3]=fmaf(w,a0.w,M1[3]);
    M1[4]=fmaf(w,a1.x,M1[4]); M1[5]=fmaf(w,a1.y,M1[5]); M1[6]=fmaf(w,a1.z,M1[6]); M1[7]=fmaf(w,a1.w,M1[7]);
    M1[8]=fmaf(w,a2.x,M1[8]); M1[9]=fmaf(w,a2.y,M1[9]); M1[10]=fmaf(w,a2.z,M1[10]); M1[11]=fmaf(w,a2.w,M1[11]);
    float4 c0 = sB4[j*3+0], c1 = sB4[j*3+1], c2 = sB4[j*3+2];
    M2[0]=fmaf(w,c0.x,M2[0]); M2[1]=fmaf(w,c0.y,M2[1]); M2[2]=fmaf(w,c0.z,M2[2]); M2[3]=fmaf(w,c0.w,M2[3]);
    M2[4]=fmaf(w,c1.x,M2[4]); M2[5]=fmaf(w,c1.y,M2[5]); M2[6]=fmaf(w,c1.z,M2[6]); M2[7]=fmaf(w,c1.w,M2[7]);
    M2[8]=fmaf(w,c2.x,M2[8]); M2[9]=fmaf(w,c2.y,M2[9]); M2[10]=fmaf(w,c2.z,M2[10]); M2[11]=fmaf(w,c2.w,M2[11]);
  }
  float a=M1[0], b=M1[1], c=M1[2];
  float d=M1[4], e=M1[5], f=M1[6];
  float g=M1[8], h=M1[9], i=M1[10];
  float C00 = e*i - f*h, C01 = c*h - b*i, C02 = b*f - c*e;
  float C10 = f*g - d*i, C11 = a*i - c*g, C12 = c*d - a*f;
  float C20 = d*h - e*g, C21 = b*g - a*h, C22 = a*e - b*d;
  float det = a*C00 + b*C10 + c*C20;
  float rd = 1.0f / det;
  float tx = px - M1[3], ty = py - M1[7], tz = pz - M1[11];
  float t0 = rd * (C00*tx + C01*ty + C02*tz);
  float t1 = rd * (C10*tx + C11*ty + C12*tz);
  float t2 = rd * (C20*tx + C21*ty + C22*tz);
  float i0 = M2[0]*t0 + M2[1]*t1 + M2[2]*t2  + M2[3];
  float i1 = M2[4]*t0 + M2[5]*t1 + M2[6]*t2  + M2[7];
  float i2 = M2[8]*t0 + M2[9]*t1 + M2[10]*t2 + M2[11];
  float d0 = rd * (C00*dx + C01*dy + C02*dz);
  float d1 = rd * (C10*dx + C11*dy + C12*dz);
  float d2 = rd * (C20*dx + C21*dy + C22*dz);
  float e0 = M2[0]*d0 + M2[1]*d1 + M2[2]*d2;
  float e1 = M2[4]*d0 + M2[5]*d1 + M2[6]*d2;
  float e2 = M2[8]*d0 + M2[9]*d1 + M2[10]*d2;

  size_t k = (size_t)n * PP + p;   // n-major
  out[O1 + k*3+0] = e0; out[O1 + k*3+1] = e1; out[O1 + k*3+2] = e2;
  out[O3 + k] = fl;
  out[O4 + k*3+0] = i0; out[O4 + k*3+1] = i1; out[O4 + k*3+2] = i2;
  out[O5 + k] = pn;
}

// grid: 1280 blocks x 256 threads. block b: p = b>>8, 128 n's.
// Mapping: 8 m-slices (s = t&7, m ≡ s mod 8) x 4 points per lane (g = t>>3,
// n0 = nb*128 + g*4). Each sPart float4 read is reused for 4 points.
// Distance expression bit-identical to the passing version.
__global__ __launch_bounds__(256) void nn_kernel(
    const float* __restrict__ pp0, const float* __restrict__ pp1,
    const float* __restrict__ part_pts, const float* __restrict__ pbw,
    const float* __restrict__ Ag, const float* __restrict__ Bg,
    const int* __restrict__ lengths2, float* __restrict__ out)
{
  __shared__ float4 sPart[MM];   // {x, y, z, |y|^2}
  __shared__ float4 sA4[72];
  __shared__ float4 sB4[72];
  int t = threadIdx.x;
  int p  = blockIdx.x >> 8;        // 256 blocks per part
  int nb = blockIdx.x & 255;
  int g  = t >> 3;                 // n-group 0..31
  int s  = t & 7;                  // m-slice 0..7
  int n0 = nb*128 + g*4;           // this lane's 4 points: n0..n0+3

  // pose-pair disambiguation (wave-uniform); pose_dirs rows unit-norm
  float s0r0 = pp0[0], s0r1 = pp0[1], s0r2 = pp0[2];
  float nrm = s0r0*s0r0 + s0r1*s0r1 + s0r2*s0r2;
  bool c0_is_dirs = fabsf(nrm - 1.0f) < 1e-4f;
  const float* pose_pts  = c0_is_dirs ? pp1 : pp0;
  const float* pose_dirs = c0_is_dirs ? pp0 : pp1;

  {
    #pragma clang fp contract(off)
    for (int i = t; i < MM; i += 256) {
      float x = part_pts[((size_t)p*MM+i)*3+0];
      float y = part_pts[((size_t)p*MM+i)*3+1];
      float z = part_pts[((size_t)p*MM+i)*3+2];
      float yy = ((x*x) + (y*y)) + (z*z);
      sPart[i] = make_float4(x, y, z, yy);
    }
  }
  for (int i = t; i < 72; i += 256) {
    int l = i*4;
    int j = l / 12, rc = l % 12;
    float4 qa, qb;
    qa.x = Ag[j*16+rc+0]; qa.y = Ag[j*16+rc+1]; qa.z = Ag[j*16+rc+2]; qa.w = Ag[j*16+rc+3];
    qb.x = Bg[j*16+rc+0]; qb.y = Bg[j*16+rc+1]; qb.z = Bg[j*16+rc+2]; qb.w = Bg[j*16+rc+3];
    sA4[i] = qa; sB4[i] = qb;
  }
  int mlen = lengths2[p]; if (mlen > MM) mlen = MM;
  __syncthreads();

  // load 4 points' coordinates (n0 % 4 == 0 -> 16B aligned)
  float X[4], Y[4], Z[4], X2[4];
  {
    #pragma clang fp contract(off)
    const float4* pr = (const float4*)(pose_pts + (size_t)n0*3);
    float4 f0 = pr[0], f1 = pr[1], f2 = pr[2];
    X[0]=f0.x; Y[0]=f0.y; Z[0]=f0.z;
    X[1]=f0.w; Y[1]=f1.x; Z[1]=f1.y;
    X[2]=f1.z; Y[2]=f1.w; Z[2]=f2.x;
    X[3]=f2.y; Y[3]=f2.z; Z[3]=f2.w;
    #pragma unroll
    for (int j = 0; j < 4; ++j)
      X2[j] = ((X[j]*X[j]) + (Y[j]*Y[j])) + (Z[j]*Z[j]);
  }

  float best[4] = {INFINITY, INFINITY, INFINITY, INFINITY};
  int   code[4] = {0, 0, 0, 0};   // best m == code*8 + s
  {
    #pragma clang fp contract(off)
    int mb = 0;
    for (; mb + 63 < mlen; mb += 64) {
      float4 q[8];
      #pragma unroll
      for (int i = 0; i < 8; ++i) q[i] = sPart[mb + s + 8*i];
      #pragma unroll
      for (int i = 0; i < 8; ++i) {
        int c = (mb >> 3) + i;     // lane-uniform (SGPR)
        #pragma unroll
        for (int j = 0; j < 4; ++j) {
          float dt = ((X[j]*q[i].x) + (Y[j]*q[i].y)) + (Z[j]*q[i].z);
          float dd = fmaxf((X2[j] - (2.0f*dt)) + q[i].w, 0.0f);
          bool lt = dd < best[j];
          best[j] = fminf(best[j], dd);
          code[j] = lt ? c : code[j];
        }
      }
    }
    for (int m = mb + s; m < mlen; m += 8) {
      float4 q = sPart[m];
      int c = (m - s) >> 3;
      #pragma unroll
      for (int j = 0; j < 4; ++j) {
        float dt = ((X[j]*q.x) + (Y[j]*q.y)) + (Z[j]*q.z);
        float dd = fmaxf((X2[j] - (2.0f*dt)) + q.w, 0.0f);
        bool lt = dd < best[j];
        best[j] = fminf(best[j], dd);
        code[j] = lt ? c : code[j];
      }
    }
  }

  // merge the 8 slices (butterfly within each 8-lane group), lexicographic
  u64_t pk[4];
  #pragma unroll
  for (int j = 0; j < 4; ++j) {
    pk[j] = ((u64_t)__float_as_uint(best[j]) << 32) | (uint_t)(code[j]*8 + s);
    u64_t o;
    o = __shfl_xor(pk[j], 1); if (o < pk[j]) pk[j] = o;
    o = __shfl_xor(pk[j], 2); if (o < pk[j]) pk[j] = o;
    o = __shfl_xor(pk[j], 4); if (o < pk[j]) pk[j] = o;
  }

  // lanes s=0..3 each transform one point (no redistribution shuffles)
  if (s < 4) {
    u64_t mypk = (s==0) ? pk[0] : (s==1) ? pk[1] : (s==2) ? pk[2] : pk[3];
    float xa = (s==0) ? X[0] : (s==1) ? X[1] : (s==2) ? X[2] : X[3];
    float ya = (s==0) ? Y[0] : (s==1) ? Y[1] : (s==2) ? Y[2] : Y[3];
    float za = (s==0) ? Z[0] : (s==1) ? Z[1] : (s==2) ? Z[2] : Z[3];
    int n = n0 + s;
    int bm = (int)(mypk & 0xFFFFFFFFull);
    float bd = __uint_as_float((uint_t)(mypk >> 32));
    float pn = sqrtf(bd);
    float fl = ((double)pn < 0.08) ? 1.0f : 0.0f;
    float dxa = pose_dirs[n*3+0], dya = pose_dirs[n*3+1], dza = pose_dirs[n*3+2];
    transform_one(n, p, bm, pn, fl, xa, ya, za, dxa, dya, dza, pbw, sA4, sB4, out);
  }
}

// ---------------- MLP via bf16 MFMA, 32 rows/wave ----------------
// grid: 1280 blocks x 256 threads (4 waves); 128 rows/block, 32 rows/wave.
// MFMA orientation = round-2-verified: mfma(A=h1frag, B=W2frag) ->
// lane holds h2[row=quad*4+reg (+tile*16)][col=nt*16+m16].
// Epilogue optimized with ZERO numerical change: {W3[c],b2[c]} packed as one
// float4 and hoisted per-nt (col=nt*16+m16 is (tile,reg)-independent) ->
// 32 ds_read_b128 instead of 512 ds_read_b32; per-(tile,reg) accumulation
// order over nt preserved exactly. Writer-tail fl/init loads spread across
// lanes early and fetched via shuffle (hides L2 latency under epilogue math).
__global__ __launch_bounds__(256, 3) void mlp_kernel(
    const float* __restrict__ W1g, const float* __restrict__ b1g,
    const float* __restrict__ b2g, const float* __restrict__ W3g,
    const float* __restrict__ b3g, const ushort_t* __restrict__ W2bf,
    float* __restrict__ out)
{
  __shared__ struct {
    float4   w1c[256];     // {W1[0][c], W1[1][c], W1[2][c], b1[c]}
    float4   w3b2[256];    // {W3[c][0], W3[c][1], W3[c][2], b2[c]}
    float    b3v[4];
    ushort_t B[2][8192];   // double-buffered W2 kc-chunk (16KB each)
  } sm;

  int t = threadIdx.x;
  int wave = t >> 6, lane = t & 63, quad = lane >> 4, m16 = lane & 15;
  size_t row0 = (size_t)blockIdx.x * 128 + (size_t)wave * 32;

  // DMA staging of one 16KB W2 kc-chunk (linear, per-wave 4KB)
  auto stage = [&](int buf, int kc) {
    const ushort_t* src = W2bf + kc*8192 + wave*2048 + lane*8;
    #pragma unroll
    for (int i = 0; i < 4; ++i) {
      __builtin_amdgcn_global_load_lds(
        (const __attribute__((address_space(1))) void*)(src + i*512),
        (__attribute__((address_space(3))) void*)(&sm.B[buf][wave*2048 + i*512]),
        16, 0, 0);
    }
  };
  stage(0, 0);

  {
    int c = t;   // 256 threads exactly
    sm.w1c[c]  = make_float4(W1g[c], W1g[256+c], W1g[512+c], b1g[c]);
    sm.w3b2[c] = make_float4(W3g[c*3+0], W3g[c*3+1], W3g[c*3+2], b2g[c]);
    if (c < 4) sm.b3v[c] = (c < 3) ? b3g[c] : 0.f;
  }

  int r0 = (int)row0 + m16;        // M-tile 0 row for this lane
  int r1 = r0 + 16;                // M-tile 1 row
  float x0 = out[O4 + (size_t)r0*3+0], y0 = out[O4 + (size_t)r0*3+1], z0 = out[O4 + (size_t)r0*3+2];
  float x1 = out[O4 + (size_t)r1*3+0], y1 = out[O4 + (size_t)r1*3+1], z1 = out[O4 + (size_t)r1*3+2];

  f32x4 acc0[16], acc1[16];
  #pragma unroll
  for (int nt = 0; nt < 16; ++nt) {
    acc0[nt] = (f32x4){0.f,0.f,0.f,0.f};
    acc1[nt] = (f32x4){0.f,0.f,0.f,0.f};
  }

  int cur = 0;
  for (int kc = 0; kc < 8; ++kc) {
    asm volatile("s_waitcnt vmcnt(0)" ::: "memory");
    __syncthreads();                      // staged chunk `cur` + params visible
    if (kc < 7) stage(cur ^ 1, kc + 1);   // prefetch next chunk under compute

    // h1 fragments for this lane's two rows, columns c0..c0+7
    union { bf16x8 v; uint_t u[4]; } ua0, ua1;
    int c0 = kc*32 + quad*8;
    #pragma unroll
    for (int jj = 0; jj < 4; ++jj) {
      float4 wA = sm.w1c[c0 + 2*jj];
      float4 wB = sm.w1c[c0 + 2*jj + 1];
      float hA0 = fmaxf(fmaf(z0, wA.z, fmaf(y0, wA.y, fmaf(x0, wA.x, wA.w))), 0.f);
      float hB0 = fmaxf(fmaf(z0, wB.z, fmaf(y0, wB.y, fmaf(x0, wB.x, wB.w))), 0.f);
      float hA1 = fmaxf(fmaf(z1, wA.z, fmaf(y1, wA.y, fmaf(x1, wA.x, wA.w))), 0.f);
      float hB1 = fmaxf(fmaf(z1, wB.z, fmaf(y1, wB.y, fmaf(x1, wB.x, wB.w))), 0.f);
      ua0.u[jj] = cvt_pk_bf16(hA0, hB0);
      ua1.u[jj] = cvt_pk_bf16(hA1, hB1);
    }

    const ushort_t* Bk = &sm.B[cur][lane*8];
    #pragma unroll
    for (int nt = 0; nt < 16; ++nt) {
      bf16x8 Bw = *(const bf16x8*)(Bk + nt*512);
      acc0[nt] = __builtin_amdgcn_mfma_f32_16x16x32_bf16(ua0.v, Bw, acc0[nt], 0, 0, 0);
      acc1[nt] = __builtin_amdgcn_mfma_f32_16x16x32_bf16(ua1.v, Bw, acc1[nt], 0, 0, 0);
    }
    cur ^= 1;
  }

  // epilogue: h2[row=tile*16+quad*4+reg][col=nt*16+m16]; layer-3 f32 + 16-lane reduce
  // spread writer-row loads across lanes (rows row0..row0+31), fetch via shuffle
  float flv = out[O3 + row0 + (size_t)(lane & 31)];
  float ivx = out[O4 + (row0 + (size_t)(lane & 31))*3 + 0];
  float ivy = out[O4 + (row0 + (size_t)(lane & 31))*3 + 1];
  float ivz = out[O4 + (row0 + (size_t)(lane & 31))*3 + 2];

  #pragma unroll
  for (int tile = 0; tile < 2; ++tile) {
    float pr[4][3];
    #pragma unroll
    for (int reg = 0; reg < 4; ++reg) { pr[reg][0]=0.f; pr[reg][1]=0.f; pr[reg][2]=0.f; }
    #pragma unroll
    for (int nt = 0; nt < 16; ++nt) {
      float4 cv = sm.w3b2[nt*16 + m16];    // {W3[col], b2[col]}, col=nt*16+m16
      #pragma unroll
      for (int reg = 0; reg < 4; ++reg) {
        float h2v = tile ? acc1[nt][reg] : acc0[nt][reg];
        float h2 = fmaxf(h2v + cv.w, 0.f);
        pr[reg][0] = fmaf(h2, cv.x, pr[reg][0]);
        pr[reg][1] = fmaf(h2, cv.y, pr[reg][1]);
        pr[reg][2] = fmaf(h2, cv.z, pr[reg][2]);
      }
    }
    #pragma unroll
    for (int reg = 0; reg < 4; ++reg) {
      float p0 = pr[reg][0], p1 = pr[reg][1], p2 = pr[reg][2];
      #pragma unroll
      for (int mask = 1; mask < 16; mask <<= 1) {
        p0 += __shfl_xor(p0, mask);
        p1 += __shfl_xor(p1, mask);
        p2 += __shfl_xor(p2, mask);
      }
      int src = tile*16 + quad*4 + reg;    // row offset within the wave's 32 rows
      float fl = __shfl(flv, src);
      float i0 = __shfl(ivx, src);
      float i1 = __shfl(ivy, src);
      float i2 = __shfl(ivz, src);
      if (m16 == 0) {
        int r = (int)row0 + src;
        float rr0 = 0.05f * tanh_fast(p0 + sm.b3v[0]) * fl;
        float rr1 = 0.05f * tanh_fast(p1 + sm.b3v[1]) * fl;
        float rr2 = 0.05f * tanh_fast(p2 + sm.b3v[2]) * fl;
        out[O0 + (size_t)r*3+0] = i0 + rr0;
        out[O0 + (size_t)r*3+1] = i1 + rr1;
        out[O0 + (size_t)r*3+2] = i2 + rr2;
        out[O2 + (size_t)r*3+0] = rr0;
        out[O2 + (size_t)r*3+1] = rr1;
        out[O2 + (size_t)r*3+2] = rr2;
      }
    }
  }
}

extern "C" void kernel_launch(void* const* d_in, const int* in_sizes, int n_in,
                              void* d_out, int out_size, void* d_ws, size_t ws_size,
                              hipStream_t stream) {
  (void)out_size; (void)ws_size;
  // size-based slot remap (no-op under documented dict order; protective otherwise)
  const int want[13] = {98304, 98304, 15360, 122880, 384, 384, 768, 256, 65536, 256, 768, 3, 5};
  int idx[13];
  bool used[64] = {false};
  for (int L = 0; L < 13; ++L) {
    idx[L] = -1;
    for (int s = 0; s < n_in && s < 64; ++s) {
      if (!used[s] && in_sizes[s] == want[L]) { idx[L] = s; used[s] = true; break; }
    }
    if (idx[L] < 0) idx[L] = L;
  }
  const float* pp0       = (const float*)d_in[idx[0]];
  const float* pp1       = (const float*)d_in[idx[1]];
  const float* part_pts  = (const float*)d_in[idx[2]];
  const float* part_pbw  = (const float*)d_in[idx[3]];
  const float* A         = (const float*)d_in[idx[4]];
  const float* bigA      = (const float*)d_in[idx[5]];
  const float* W1        = (const float*)d_in[idx[6]];
  const float* b1        = (const float*)d_in[idx[7]];
  const float* W2        = (const float*)d_in[idx[8]];
  const float* b2        = (const float*)d_in[idx[9]];
  const float* W3        = (const float*)d_in[idx[10]];
  const float* b3        = (const float*)d_in[idx[11]];
  const int*   lengths2  = (const int*)d_in[idx[12]];
  float* out = (float*)d_out;
  ushort_t* W2bf = (ushort_t*)d_ws;   // 128 KB of workspace

  prep_w2<<<256, 256, 0, stream>>>(W2, W2bf);
  nn_kernel<<<1280, 256, 0, stream>>>(pp0, pp1, part_pts, part_pbw,
                                      A, bigA, lengths2, out);
  mlp_kernel<<<1280, 256, 0, stream>>>(W1, b1, b2, W3, b3, W2bf, out);
}

// Round 5
// 188.928 us; speedup vs baseline: 1.1128x; 1.1128x over previous
//
#include <hip/hip_runtime.h>
#include <stdint.h>
#include <math.h>

// Problem constants
#define NPTS 32768
#define PP   5
#define MM   1024
#define JJ   24
#define HH   256

// out (f32 element offsets), total 2,293,760 floats
#define O0 0                // tpose        [1,N,P,3]
#define O1 491520           // tpose_dirs   [1,N,P,3]
#define O2 983040           // resd         [1,N,P,3]
#define O3 1474560          // pflag        [1,N,P]
#define O4 1638400          // init_bigpose [1,N*P,3]
#define O5 2129920          // pnorm        [1,N*P]

typedef unsigned short ushort_t;
typedef unsigned int   uint_t;
typedef unsigned long long u64_t;
typedef __attribute__((ext_vector_type(8))) short bf16x8;
typedef __attribute__((ext_vector_type(4))) float f32x4;

__device__ __forceinline__ ushort_t f2bf(float f) {
  union { uint_t i; float f; } v; v.f = f;
  uint_t i = v.i;
  return (ushort_t)((i + 0x7FFFu + ((i >> 16) & 1u)) >> 16);  // RNE
}
// hardware packed f32->bf16 (RNE, bit-identical to f2bf for finite values)
__device__ __forceinline__ uint_t cvt_pk_bf16(float lo, float hi) {
  uint_t r;
  asm("v_cvt_pk_bf16_f32 %0, %1, %2" : "=v"(r) : "v"(lo), "v"(hi));
  return r;
}
__device__ __forceinline__ float tanh_fast(float v) {
  v = fminf(fmaxf(v, -15.f), 15.f);
  float e = __expf(2.f*v);               // v_exp_f32 path
  return __fdividef(e - 1.f, e + 1.f);   // abs err < 1e-6, plenty for tolerance
}

// ---------------- prep: W2 f32 -> bf16 in MFMA B-fragment order ----------------
// idx = kc*8192 + tile*512 + lane*8 + j  (lane=quad*16+(n&15), quad=(k&31)>>3, j=k&7)
__global__ __launch_bounds__(256) void prep_w2(const float* __restrict__ W2g,
                                               ushort_t* __restrict__ W2bf)
{
  int k = blockIdx.x;
  int n = threadIdx.x;
  float v = W2g[k*256 + n];
  int kc = k >> 5, quad = (k & 31) >> 3, j = k & 7;
  int tile = n >> 4, lane = quad*16 + (n & 15);
  W2bf[kc*8192 + tile*512 + lane*8 + j] = f2bf(v);
}

// ---------------- LBS transform for one (n,p) row ----------------
__device__ __forceinline__ void transform_one(
    int n, int p, int nn, float pn, float fl,
    float px, float py, float pz, float dx, float dy, float dz,
    const float* __restrict__ pbw,
    const float4* __restrict__ sA4, const float4* __restrict__ sB4,
    float* __restrict__ out)
{
  const float4* bwr = (const float4*)(pbw + ((size_t)p * MM + nn) * JJ);
  float bw[24];
  #pragma unroll
  for (int q = 0; q < 6; ++q) {
    float4 u = bwr[q];
    bw[q*4+0] = u.x; bw[q*4+1] = u.y; bw[q*4+2] = u.z; bw[q*4+3] = u.w;
  }

  float M1[12], M2[12];
  #pragma unroll
  for (int q = 0; q < 12; ++q) { M1[q] = 0.f; M2[q] = 0.f; }
  #pragma unroll
  for (int j = 0; j < 24; ++j) {
    float w = bw[j];
    float4 a0 = sA4[j*3+0], a1 = sA4[j*3+1], a2 = sA4[j*3+2];
    M1[0]=fmaf(w,a0.x,M1[0]); M1[1]=fmaf(w,a0.y,M1[1]); M1[2]=fmaf(w,a0.z,M1[2]); M1[3]=fmaf(w,a0.w,M1[3]);
    M1[4]=fmaf(w,a1.x,M1[4]); M1[5]=fmaf(w,a1.y,M1[5]); M1[6]=fmaf(w,a1.z,M1[6]); M1[7]=fmaf(w,a1.w,M1[7]);
    M1[8]=fmaf(w,a2.x,M1[8]); M1[9]=fmaf(w,a2.y,M1[9]); M1[10]=fmaf(w,a2.z,M1[10]); M1[11]=fmaf(w,a2.w,M1[11]);
    float4 c0 = sB4[j*3+0], c1 = sB4[j*3+1], c2 = sB4[j*3+2];
    M2[0]=fmaf(w,c0.x,M2[0]); M2[1]=fmaf(w,c0.y,M2[1]); M2[2]=fmaf(w,c0.z,M2[2]); M2[3]=fmaf(w,c0.w,M2[3]);
    M2[4]=fmaf(w,c1.x,M2[4]); M2[5]=fmaf(w,c1.y,M2[5]); M2[6]=fmaf(w,c1.z,M2[6]); M2[7]=fmaf(w,c1.w,M2[7]);
    M2[8]=fmaf(w,c2.x,M2[8]); M2[9]=fmaf(w,c2.y,M2[9]); M2[10]=fmaf(w,c2.z,M2[10]); M2[11]=fmaf(w,c2.w,M2[11]);
  }
  float a=M1[0], b=M1[1], c=M1[2];
  float d=M1[4], e=M1[5], f=M1[6];
  float g=M1[8], h=M1[9], i=M1[10];
  float C00 = e*i - f*h, C01 = c*h - b*i, C02 = b*f - c*e;
  float C10 = f*g - d*i, C11 = a*i - c*g, C12 = c*d - a*f;
  float C20 = d*h - e*g, C21 = b*g - a*h, C22 = a*e - b*d;
  float det = a*C00 + b*C10 + c*C20;
  float rd = 1.0f / det;
  float tx = px - M1[3], ty = py - M1[7], tz = pz - M1[11];
  float t0 = rd * (C00*tx + C01*ty + C02*tz);
  float t1 = rd * (C10*tx + C11*ty + C12*tz);
  float t2 = rd * (C20*tx + C21*ty + C22*tz);
  float i0 = M2[0]*t0 + M2[1]*t1 + M2[2]*t2  + M2[3];
  float i1 = M2[4]*t0 + M2[5]*t1 + M2[6]*t2  + M2[7];
  float i2 = M2[8]*t0 + M2[9]*t1 + M2[10]*t2 + M2[11];
  float d0 = rd * (C00*dx + C01*dy + C02*dz);
  float d1 = rd * (C10*dx + C11*dy + C12*dz);
  float d2 = rd * (C20*dx + C21*dy + C22*dz);
  float e0 = M2[0]*d0 + M2[1]*d1 + M2[2]*d2;
  float e1 = M2[4]*d0 + M2[5]*d1 + M2[6]*d2;
  float e2 = M2[8]*d0 + M2[9]*d1 + M2[10]*d2;

  size_t k = (size_t)n * PP + p;   // n-major
  out[O1 + k*3+0] = e0; out[O1 + k*3+1] = e1; out[O1 + k*3+2] = e2;
  out[O3 + k] = fl;
  out[O4 + k*3+0] = i0; out[O4 + k*3+1] = i1; out[O4 + k*3+2] = i2;
  out[O5 + k] = pn;
}

// grid: 1280 blocks x 256 threads. block b: p = b>>8, 128 n's.
// Mapping: 8 m-slices (s = t&7, m ≡ s mod 8) x 4 points per lane (g = t>>3,
// n0 = nb*128 + g*4). Each sPart float4 read is reused for 4 points.
// Distance expression bit-identical to the passing version.
__global__ __launch_bounds__(256) void nn_kernel(
    const float* __restrict__ pp0, const float* __restrict__ pp1,
    const float* __restrict__ part_pts, const float* __restrict__ pbw,
    const float* __restrict__ Ag, const float* __restrict__ Bg,
    const int* __restrict__ lengths2, float* __restrict__ out)
{
  __shared__ float4 sPart[MM];   // {x, y, z, |y|^2}
  __shared__ float4 sA4[72];
  __shared__ float4 sB4[72];
  int t = threadIdx.x;
  int p  = blockIdx.x >> 8;        // 256 blocks per part
  int nb = blockIdx.x & 255;
  int g  = t >> 3;                 // n-group 0..31
  int s  = t & 7;                  // m-slice 0..7
  int n0 = nb*128 + g*4;           // this lane's 4 points: n0..n0+3

  // pose-pair disambiguation (wave-uniform); pose_dirs rows unit-norm
  float s0r0 = pp0[0], s0r1 = pp0[1], s0r2 = pp0[2];
  float nrm = s0r0*s0r0 + s0r1*s0r1 + s0r2*s0r2;
  bool c0_is_dirs = fabsf(nrm - 1.0f) < 1e-4f;
  const float* pose_pts  = c0_is_dirs ? pp1 : pp0;
  const float* pose_dirs = c0_is_dirs ? pp0 : pp1;

  {
    #pragma clang fp contract(off)
    for (int i = t; i < MM; i += 256) {
      float x = part_pts[((size_t)p*MM+i)*3+0];
      float y = part_pts[((size_t)p*MM+i)*3+1];
      float z = part_pts[((size_t)p*MM+i)*3+2];
      float yy = ((x*x) + (y*y)) + (z*z);
      sPart[i] = make_float4(x, y, z, yy);
    }
  }
  for (int i = t; i < 72; i += 256) {
    int l = i*4;
    int j = l / 12, rc = l % 12;
    float4 qa, qb;
    qa.x = Ag[j*16+rc+0]; qa.y = Ag[j*16+rc+1]; qa.z = Ag[j*16+rc+2]; qa.w = Ag[j*16+rc+3];
    qb.x = Bg[j*16+rc+0]; qb.y = Bg[j*16+rc+1]; qb.z = Bg[j*16+rc+2]; qb.w = Bg[j*16+rc+3];
    sA4[i] = qa; sB4[i] = qb;
  }
  int mlen = lengths2[p]; if (mlen > MM) mlen = MM;
  __syncthreads();

  // load 4 points' coordinates (n0 % 4 == 0 -> 16B aligned)
  float X[4], Y[4], Z[4], X2[4];
  {
    #pragma clang fp contract(off)
    const float4* pr = (const float4*)(pose_pts + (size_t)n0*3);
    float4 f0 = pr[0], f1 = pr[1], f2 = pr[2];
    X[0]=f0.x; Y[0]=f0.y; Z[0]=f0.z;
    X[1]=f0.w; Y[1]=f1.x; Z[1]=f1.y;
    X[2]=f1.z; Y[2]=f1.w; Z[2]=f2.x;
    X[3]=f2.y; Y[3]=f2.z; Z[3]=f2.w;
    #pragma unroll
    for (int j = 0; j < 4; ++j)
      X2[j] = ((X[j]*X[j]) + (Y[j]*Y[j])) + (Z[j]*Z[j]);
  }

  float best[4] = {INFINITY, INFINITY, INFINITY, INFINITY};
  int   code[4] = {0, 0, 0, 0};   // best m == code*8 + s
  {
    #pragma clang fp contract(off)
    int mb = 0;
    for (; mb + 63 < mlen; mb += 64) {
      float4 q[8];
      #pragma unroll
      for (int i = 0; i < 8; ++i) q[i] = sPart[mb + s + 8*i];
      #pragma unroll
      for (int i = 0; i < 8; ++i) {
        int c = (mb >> 3) + i;     // lane-uniform (SGPR)
        #pragma unroll
        for (int j = 0; j < 4; ++j) {
          float dt = ((X[j]*q[i].x) + (Y[j]*q[i].y)) + (Z[j]*q[i].z);
          float dd = fmaxf((X2[j] - (2.0f*dt)) + q[i].w, 0.0f);
          bool lt = dd < best[j];
          best[j] = fminf(best[j], dd);
          code[j] = lt ? c : code[j];
        }
      }
    }
    for (int m = mb + s; m < mlen; m += 8) {
      float4 q = sPart[m];
      int c = (m - s) >> 3;
      #pragma unroll
      for (int j = 0; j < 4; ++j) {
        float dt = ((X[j]*q.x) + (Y[j]*q.y)) + (Z[j]*q.z);
        float dd = fmaxf((X2[j] - (2.0f*dt)) + q.w, 0.0f);
        bool lt = dd < best[j];
        best[j] = fminf(best[j], dd);
        code[j] = lt ? c : code[j];
      }
    }
  }

  // merge the 8 slices (butterfly within each 8-lane group), lexicographic
  u64_t pk[4];
  #pragma unroll
  for (int j = 0; j < 4; ++j) {
    pk[j] = ((u64_t)__float_as_uint(best[j]) << 32) | (uint_t)(code[j]*8 + s);
    u64_t o;
    o = __shfl_xor(pk[j], 1); if (o < pk[j]) pk[j] = o;
    o = __shfl_xor(pk[j], 2); if (o < pk[j]) pk[j] = o;
    o = __shfl_xor(pk[j], 4); if (o < pk[j]) pk[j] = o;
  }

  // lanes s=0..3 each transform one point (no redistribution shuffles)
  if (s < 4) {
    u64_t mypk = (s==0) ? pk[0] : (s==1) ? pk[1] : (s==2) ? pk[2] : pk[3];
    float xa = (s==0) ? X[0] : (s==1) ? X[1] : (s==2) ? X[2] : X[3];
    float ya = (s==0) ? Y[0] : (s==1) ? Y[1] : (s==2) ? Y[2] : Y[3];
    float za = (s==0) ? Z[0] : (s==1) ? Z[1] : (s==2) ? Z[2] : Z[3];
    int n = n0 + s;
    int bm = (int)(mypk & 0xFFFFFFFFull);
    float bd = __uint_as_float((uint_t)(mypk >> 32));
    float pn = sqrtf(bd);
    float fl = ((double)pn < 0.08) ? 1.0f : 0.0f;
    float dxa = pose_dirs[n*3+0], dya = pose_dirs[n*3+1], dza = pose_dirs[n*3+2];
    transform_one(n, p, bm, pn, fl, xa, ya, za, dxa, dya, dza, pbw, sA4, sB4, out);
  }
}

// ---------------- MLP via bf16 MFMA, 16 rows/wave ----------------
// grid: 2560 blocks x 256 threads (4 waves); 64 rows/block, 16 rows/wave.
// 16 rows/wave halves the accumulator footprint (64 VGPRs vs 128) so the
// kernel honestly fits 4 waves/SIMD without spill (round-4 lesson: the
// (256,3) launch bound forced VGPR=84 -> acc spilled to scratch, 125MB of
// HBM traffic). LDS trimmed to exactly 40KB (B first, b3 read from global)
// -> 4 blocks/CU. Per-row math bit-identical to the verified round-2/4 path:
// same A-build expressions, same kc/nt MFMA order, same packed epilogue.
__global__ __launch_bounds__(256) void mlp_kernel(
    const float* __restrict__ W1g, const float* __restrict__ b1g,
    const float* __restrict__ b2g, const float* __restrict__ W3g,
    const float* __restrict__ b3g, const ushort_t* __restrict__ W2bf,
    float* __restrict__ out)
{
  __shared__ struct {
    ushort_t B[2][8192];   // double-buffered W2 kc-chunk (16KB each)
    float4   w1c[256];     // {W1[0][c], W1[1][c], W1[2][c], b1[c]}
    float4   w3b2[256];    // {W3[c][0], W3[c][1], W3[c][2], b2[c]}
  } sm;                    // 40960 B exactly -> 4 blocks/CU

  int t = threadIdx.x;
  int wave = t >> 6, lane = t & 63, quad = lane >> 4, m16 = lane & 15;
  size_t row0 = (size_t)blockIdx.x * 64 + (size_t)wave * 16;

  // DMA staging of one 16KB W2 kc-chunk (linear, per-wave 4KB)
  auto stage = [&](int buf, int kc) {
    const ushort_t* src = W2bf + kc*8192 + wave*2048 + lane*8;
    #pragma unroll
    for (int i = 0; i < 4; ++i) {
      __builtin_amdgcn_global_load_lds(
        (const __attribute__((address_space(1))) void*)(src + i*512),
        (__attribute__((address_space(3))) void*)(&sm.B[buf][wave*2048 + i*512]),
        16, 0, 0);
    }
  };
  stage(0, 0);

  {
    int c = t;   // 256 threads exactly
    sm.w1c[c]  = make_float4(W1g[c], W1g[256+c], W1g[512+c], b1g[c]);
    sm.w3b2[c] = make_float4(W3g[c*3+0], W3g[c*3+1], W3g[c*3+2], b2g[c]);
  }

  int r0 = (int)row0 + m16;        // this lane's row
  float x0 = out[O4 + (size_t)r0*3+0], y0 = out[O4 + (size_t)r0*3+1], z0 = out[O4 + (size_t)r0*3+2];

  f32x4 acc0[16];
  #pragma unroll
  for (int nt = 0; nt < 16; ++nt) acc0[nt] = (f32x4){0.f,0.f,0.f,0.f};

  int cur = 0;
  for (int kc = 0; kc < 8; ++kc) {
    asm volatile("s_waitcnt vmcnt(0)" ::: "memory");
    __syncthreads();                      // staged chunk `cur` + params visible
    if (kc < 7) stage(cur ^ 1, kc + 1);   // prefetch next chunk under compute

    // h1 fragment for this lane's row, columns c0..c0+7
    union { bf16x8 v; uint_t u[4]; } ua0;
    int c0 = kc*32 + quad*8;
    #pragma unroll
    for (int jj = 0; jj < 4; ++jj) {
      float4 wA = sm.w1c[c0 + 2*jj];
      float4 wB = sm.w1c[c0 + 2*jj + 1];
      float hA0 = fmaxf(fmaf(z0, wA.z, fmaf(y0, wA.y, fmaf(x0, wA.x, wA.w))), 0.f);
      float hB0 = fmaxf(fmaf(z0, wB.z, fmaf(y0, wB.y, fmaf(x0, wB.x, wB.w))), 0.f);
      ua0.u[jj] = cvt_pk_bf16(hA0, hB0);
    }

    const ushort_t* Bk = &sm.B[cur][lane*8];
    #pragma unroll
    for (int nt = 0; nt < 16; ++nt) {
      bf16x8 Bw = *(const bf16x8*)(Bk + nt*512);
      acc0[nt] = __builtin_amdgcn_mfma_f32_16x16x32_bf16(ua0.v, Bw, acc0[nt], 0, 0, 0);
    }
    cur ^= 1;
  }

  // epilogue: h2[row=quad*4+reg][col=nt*16+m16]; layer-3 f32 + 16-lane reduce.
  // spread writer-row loads across lanes (rows row0..row0+15), fetch via shuffle
  float flv = out[O3 + row0 + (size_t)m16];
  float ivx = out[O4 + (row0 + (size_t)m16)*3 + 0];
  float ivy = out[O4 + (row0 + (size_t)m16)*3 + 1];
  float ivz = out[O4 + (row0 + (size_t)m16)*3 + 2];

  float pr[4][3];
  #pragma unroll
  for (int reg = 0; reg < 4; ++reg) { pr[reg][0]=0.f; pr[reg][1]=0.f; pr[reg][2]=0.f; }
  #pragma unroll
  for (int nt = 0; nt < 16; ++nt) {
    float4 cv = sm.w3b2[nt*16 + m16];    // {W3[col], b2[col]}, col=nt*16+m16
    #pragma unroll
    for (int reg = 0; reg < 4; ++reg) {
      float h2 = fmaxf(acc0[nt][reg] + cv.w, 0.f);
      pr[reg][0] = fmaf(h2, cv.x, pr[reg][0]);
      pr[reg][1] = fmaf(h2, cv.y, pr[reg][1]);
      pr[reg][2] = fmaf(h2, cv.z, pr[reg][2]);
    }
  }
  float b30 = b3g[0], b31 = b3g[1], b32 = b3g[2];   // uniform s_loads
  #pragma unroll
  for (int reg = 0; reg < 4; ++reg) {
    float p0 = pr[reg][0], p1 = pr[reg][1], p2 = pr[reg][2];
    #pragma unroll
    for (int mask = 1; mask < 16; mask <<= 1) {
      p0 += __shfl_xor(p0, mask);
      p1 += __shfl_xor(p1, mask);
      p2 += __shfl_xor(p2, mask);
    }
    int src = quad*4 + reg;              // row offset within the wave's 16 rows
    float fl = __shfl(flv, src);
    float i0 = __shfl(ivx, src);
    float i1 = __shfl(ivy, src);
    float i2 = __shfl(ivz, src);
    if (m16 == 0) {
      int r = (int)row0 + src;
      float rr0 = 0.05f * tanh_fast(p0 + b30) * fl;
      float rr1 = 0.05f * tanh_fast(p1 + b31) * fl;
      float rr2 = 0.05f * tanh_fast(p2 + b32) * fl;
      out[O0 + (size_t)r*3+0] = i0 + rr0;
      out[O0 + (size_t)r*3+1] = i1 + rr1;
      out[O0 + (size_t)r*3+2] = i2 + rr2;
      out[O2 + (size_t)r*3+0] = rr0;
      out[O2 + (size_t)r*3+1] = rr1;
      out[O2 + (size_t)r*3+2] = rr2;
    }
  }
}

extern "C" void kernel_launch(void* const* d_in, const int* in_sizes, int n_in,
                              void* d_out, int out_size, void* d_ws, size_t ws_size,
                              hipStream_t stream) {
  (void)out_size; (void)ws_size;
  // size-based slot remap (no-op under documented dict order; protective otherwise)
  const int want[13] = {98304, 98304, 15360, 122880, 384, 384, 768, 256, 65536, 256, 768, 3, 5};
  int idx[13];
  bool used[64] = {false};
  for (int L = 0; L < 13; ++L) {
    idx[L] = -1;
    for (int s = 0; s < n_in && s < 64; ++s) {
      if (!used[s] && in_sizes[s] == want[L]) { idx[L] = s; used[s] = true; break; }
    }
    if (idx[L] < 0) idx[L] = L;
  }
  const float* pp0       = (const float*)d_in[idx[0]];
  const float* pp1       = (const float*)d_in[idx[1]];
  const float* part_pts  = (const float*)d_in[idx[2]];
  const float* part_pbw  = (const float*)d_in[idx[3]];
  const float* A         = (const float*)d_in[idx[4]];
  const float* bigA      = (const float*)d_in[idx[5]];
  const float* W1        = (const float*)d_in[idx[6]];
  const float* b1        = (const float*)d_in[idx[7]];
  const float* W2        = (const float*)d_in[idx[8]];
  const float* b2        = (const float*)d_in[idx[9]];
  const float* W3        = (const float*)d_in[idx[10]];
  const float* b3        = (const float*)d_in[idx[11]];
  const int*   lengths2  = (const int*)d_in[idx[12]];
  float* out = (float*)d_out;
  ushort_t* W2bf = (ushort_t*)d_ws;   // 128 KB of workspace

  prep_w2<<<256, 256, 0, stream>>>(W2, W2bf);
  nn_kernel<<<1280, 256, 0, stream>>>(pp0, pp1, part_pts, part_pbw,
                                      A, bigA, lengths2, out);
  mlp_kernel<<<2560, 256, 0, stream>>>(W1, b1, b2, W3, b3, W2bf, out);
}

// Round 6
// 176.842 us; speedup vs baseline: 1.1889x; 1.0683x over previous
//
#include <hip/hip_runtime.h>
#include <stdint.h>
#include <math.h>

// Problem constants
#define NPTS 32768
#define PP   5
#define MM   1024
#define JJ   24
#define HH   256

// out (f32 element offsets), total 2,293,760 floats
#define O0 0                // tpose        [1,N,P,3]
#define O1 491520           // tpose_dirs   [1,N,P,3]
#define O2 983040           // resd         [1,N,P,3]
#define O3 1474560          // pflag        [1,N,P]
#define O4 1638400          // init_bigpose [1,N*P,3]
#define O5 2129920          // pnorm        [1,N*P]

typedef unsigned short ushort_t;
typedef unsigned int   uint_t;
typedef unsigned long long u64_t;
typedef __attribute__((ext_vector_type(8))) short bf16x8;
typedef __attribute__((ext_vector_type(4))) float f32x4;
typedef __attribute__((ext_vector_type(2))) float f32x2;

__device__ __forceinline__ ushort_t f2bf(float f) {
  union { uint_t i; float f; } v; v.f = f;
  uint_t i = v.i;
  return (ushort_t)((i + 0x7FFFu + ((i >> 16) & 1u)) >> 16);  // RNE
}
// hardware packed f32->bf16 (RNE, bit-identical to f2bf for finite values)
__device__ __forceinline__ uint_t cvt_pk_bf16(float lo, float hi) {
  uint_t r;
  asm("v_cvt_pk_bf16_f32 %0, %1, %2" : "=v"(r) : "v"(lo), "v"(hi));
  return r;
}
__device__ __forceinline__ float tanh_fast(float v) {
  v = fminf(fmaxf(v, -15.f), 15.f);
  float e = __expf(2.f*v);               // v_exp_f32 path
  return __fdividef(e - 1.f, e + 1.f);   // abs err < 1e-6, plenty for tolerance
}

// ---------------- LBS transform for one (n,p) row ----------------
__device__ __forceinline__ void transform_one(
    int n, int p, int nn, float pn, float fl,
    float px, float py, float pz, float dx, float dy, float dz,
    const float* __restrict__ pbw,
    const float4* __restrict__ sA4, const float4* __restrict__ sB4,
    float* __restrict__ out)
{
  const float4* bwr = (const float4*)(pbw + ((size_t)p * MM + nn) * JJ);
  float bw[24];
  #pragma unroll
  for (int q = 0; q < 6; ++q) {
    float4 u = bwr[q];
    bw[q*4+0] = u.x; bw[q*4+1] = u.y; bw[q*4+2] = u.z; bw[q*4+3] = u.w;
  }

  float M1[12], M2[12];
  #pragma unroll
  for (int q = 0; q < 12; ++q) { M1[q] = 0.f; M2[q] = 0.f; }
  #pragma unroll
  for (int j = 0; j < 24; ++j) {
    float w = bw[j];
    float4 a0 = sA4[j*3+0], a1 = sA4[j*3+1], a2 = sA4[j*3+2];
    M1[0]=fmaf(w,a0.x,M1[0]); M1[1]=fmaf(w,a0.y,M1[1]); M1[2]=fmaf(w,a0.z,M1[2]); M1[3]=fmaf(w,a0.w,M1[3]);
    M1[4]=fmaf(w,a1.x,M1[4]); M1[5]=fmaf(w,a1.y,M1[5]); M1[6]=fmaf(w,a1.z,M1[6]); M1[7]=fmaf(w,a1.w,M1[7]);
    M1[8]=fmaf(w,a2.x,M1[8]); M1[9]=fmaf(w,a2.y,M1[9]); M1[10]=fmaf(w,a2.z,M1[10]); M1[11]=fmaf(w,a2.w,M1[11]);
    float4 c0 = sB4[j*3+0], c1 = sB4[j*3+1], c2 = sB4[j*3+2];
    M2[0]=fmaf(w,c0.x,M2[0]); M2[1]=fmaf(w,c0.y,M2[1]); M2[2]=fmaf(w,c0.z,M2[2]); M2[3]=fmaf(w,c0.w,M2[3]);
    M2[4]=fmaf(w,c1.x,M2[4]); M2[5]=fmaf(w,c1.y,M2[5]); M2[6]=fmaf(w,c1.z,M2[6]); M2[7]=fmaf(w,c1.w,M2[7]);
    M2[8]=fmaf(w,c2.x,M2[8]); M2[9]=fmaf(w,c2.y,M2[9]); M2[10]=fmaf(w,c2.z,M2[10]); M2[11]=fmaf(w,c2.w,M2[11]);
  }
  float a=M1[0], b=M1[1], c=M1[2];
  float d=M1[4], e=M1[5], f=M1[6];
  float g=M1[8], h=M1[9], i=M1[10];
  float C00 = e*i - f*h, C01 = c*h - b*i, C02 = b*f - c*e;
  float C10 = f*g - d*i, C11 = a*i - c*g, C12 = c*d - a*f;
  float C20 = d*h - e*g, C21 = b*g - a*h, C22 = a*e - b*d;
  float det = a*C00 + b*C10 + c*C20;
  float rd = 1.0f / det;
  float tx = px - M1[3], ty = py - M1[7], tz = pz - M1[11];
  float t0 = rd * (C00*tx + C01*ty + C02*tz);
  float t1 = rd * (C10*tx + C11*ty + C12*tz);
  float t2 = rd * (C20*tx + C21*ty + C22*tz);
  float i0 = M2[0]*t0 + M2[1]*t1 + M2[2]*t2  + M2[3];
  float i1 = M2[4]*t0 + M2[5]*t1 + M2[6]*t2  + M2[7];
  float i2 = M2[8]*t0 + M2[9]*t1 + M2[10]*t2 + M2[11];
  float d0 = rd * (C00*dx + C01*dy + C02*dz);
  float d1 = rd * (C10*dx + C11*dy + C12*dz);
  float d2 = rd * (C20*dx + C21*dy + C22*dz);
  float e0 = M2[0]*d0 + M2[1]*d1 + M2[2]*d2;
  float e1 = M2[4]*d0 + M2[5]*d1 + M2[6]*d2;
  float e2 = M2[8]*d0 + M2[9]*d1 + M2[10]*d2;

  size_t k = (size_t)n * PP + p;   // n-major
  out[O1 + k*3+0] = e0; out[O1 + k*3+1] = e1; out[O1 + k*3+2] = e2;
  out[O3 + k] = fl;
  out[O4 + k*3+0] = i0; out[O4 + k*3+1] = i1; out[O4 + k*3+2] = i2;
  out[O5 + k] = pn;
}

// grid: 1536 blocks x 256 threads. Blocks >=1280 do the W2->bf16 prep (folded
// former prep_w2 kernel). Blocks <1280: p = b>>8, 128 n's.
// Mapping: 8 m-slices (s = t&7) x 4 points per lane (g = t>>3, n0 = nb*128+g*4).
// Each lane owns 4 CONSECUTIVE m's per 32-block (m = 32k + 4s + e, e=0..3):
// SoA LDS (X/Y/Z/|p|^2 as float4 quads) delivers 4 m's per ds_read_b128 in
// aligned VGPR pairs -> distance math runs as elementwise f32x2 ops (packed
// v_pk_mul/add_f32 when available; each component is IEEE f32 with the SAME
// association as before -> bit-exact). The 2.0f* is folded into pre-doubled
// coords: fl(2r)=2*fl(r) inductively => (x2-dt2)+qw is bit-identical to
// (x2-2.0f*dt)+qw. Min tracking is scalar and sequential in increasing m =>
// exact first-min; cross-slice merge packs (d2bits<<32|m), u64 min butterfly.
__global__ __launch_bounds__(256) void nn_kernel(
    const float* __restrict__ pp0, const float* __restrict__ pp1,
    const float* __restrict__ part_pts, const float* __restrict__ pbw,
    const float* __restrict__ Ag, const float* __restrict__ Bg,
    const int* __restrict__ lengths2,
    const float* __restrict__ W2g, ushort_t* __restrict__ W2bf,
    float* __restrict__ out)
{
  // folded W2 prep (former prep_w2): blocks 1280..1535, k = bid-1280
  if (blockIdx.x >= 1280) {
    int k = blockIdx.x - 1280;
    int n = threadIdx.x;
    float v = W2g[k*256 + n];
    int kc = k >> 5, quad = (k & 31) >> 3, j = k & 7;
    int tile = n >> 4, lane = quad*16 + (n & 15);
    W2bf[kc*8192 + tile*512 + lane*8 + j] = f2bf(v);
    return;
  }

  __shared__ float4 sXq[256], sYq[256], sZq[256], sWq[256];  // SoA quads
  __shared__ float4 sA4[72];
  __shared__ float4 sB4[72];
  int t = threadIdx.x;
  int p  = blockIdx.x >> 8;        // 256 blocks per part
  int nb = blockIdx.x & 255;
  int g  = t >> 3;                 // n-group 0..31
  int s  = t & 7;                  // m-slice 0..7
  int n0 = nb*128 + g*4;           // this lane's 4 points: n0..n0+3

  // pose-pair disambiguation (wave-uniform); pose_dirs rows unit-norm
  float s0r0 = pp0[0], s0r1 = pp0[1], s0r2 = pp0[2];
  float nrm = s0r0*s0r0 + s0r1*s0r1 + s0r2*s0r2;
  bool c0_is_dirs = fabsf(nrm - 1.0f) < 1e-4f;
  const float* pose_pts  = c0_is_dirs ? pp1 : pp0;
  const float* pose_dirs = c0_is_dirs ? pp0 : pp1;

  {
    #pragma clang fp contract(off)
    float* fX = (float*)sXq; float* fY = (float*)sYq;
    float* fZ = (float*)sZq; float* fW = (float*)sWq;
    for (int i = t; i < MM; i += 256) {
      float x = part_pts[((size_t)p*MM+i)*3+0];
      float y = part_pts[((size_t)p*MM+i)*3+1];
      float z = part_pts[((size_t)p*MM+i)*3+2];
      float yy = ((x*x) + (y*y)) + (z*z);
      fX[i] = x; fY[i] = y; fZ[i] = z; fW[i] = yy;
    }
  }
  for (int i = t; i < 72; i += 256) {
    int l = i*4;
    int j = l / 12, rc = l % 12;
    float4 qa, qb;
    qa.x = Ag[j*16+rc+0]; qa.y = Ag[j*16+rc+1]; qa.z = Ag[j*16+rc+2]; qa.w = Ag[j*16+rc+3];
    qb.x = Bg[j*16+rc+0]; qb.y = Bg[j*16+rc+1]; qb.z = Bg[j*16+rc+2]; qb.w = Bg[j*16+rc+3];
    sA4[i] = qa; sB4[i] = qb;
  }
  int mlen = lengths2[p]; if (mlen > MM) mlen = MM;
  __syncthreads();

  // load 4 points' coordinates (n0 % 4 == 0 -> 16B aligned); build doubled splats
  float X[4], Y[4], Z[4];
  f32x2 Xd[4], Yd[4], Zd[4], C2[4];
  {
    #pragma clang fp contract(off)
    const float4* pr = (const float4*)(pose_pts + (size_t)n0*3);
    float4 f0 = pr[0], f1 = pr[1], f2 = pr[2];
    X[0]=f0.x; Y[0]=f0.y; Z[0]=f0.z;
    X[1]=f0.w; Y[1]=f1.x; Z[1]=f1.y;
    X[2]=f1.z; Y[2]=f1.w; Z[2]=f2.x;
    X[3]=f2.y; Y[3]=f2.z; Z[3]=f2.w;
    #pragma unroll
    for (int j = 0; j < 4; ++j) {
      float x2 = ((X[j]*X[j]) + (Y[j]*Y[j])) + (Z[j]*Z[j]);
      Xd[j] = (f32x2){2.0f*X[j], 2.0f*X[j]};
      Yd[j] = (f32x2){2.0f*Y[j], 2.0f*Y[j]};
      Zd[j] = (f32x2){2.0f*Z[j], 2.0f*Z[j]};
      C2[j] = (f32x2){x2, x2};
    }
  }

  float best[4] = {INFINITY, INFINITY, INFINITY, INFINITY};
  int   code[4] = {0, 0, 0, 0};   // best m == ((code>>2)<<5) + 4*s + (code&3)
  {
    #pragma clang fp contract(off)
    int nq = mlen >> 5;                // full 32-blocks
    for (int k = 0; k < nq; ++k) {
      int qi = k*8 + s;                // quad index (8-way same-addr broadcast)
      float4 QX = sXq[qi], QY = sYq[qi], QZ = sZq[qi], QW = sWq[qi];
      f32x2 qx0 = {QX.x, QX.y}, qx1 = {QX.z, QX.w};
      f32x2 qy0 = {QY.x, QY.y}, qy1 = {QY.z, QY.w};
      f32x2 qz0 = {QZ.x, QZ.y}, qz1 = {QZ.z, QZ.w};
      f32x2 qw0 = {QW.x, QW.y}, qw1 = {QW.z, QW.w};
      int cb = k << 2;                 // lane-uniform (SGPR)
      #pragma unroll
      for (int j = 0; j < 4; ++j) {
        f32x2 dt0 = ((Xd[j]*qx0) + (Yd[j]*qy0)) + (Zd[j]*qz0);
        f32x2 tt0 = (C2[j] - dt0) + qw0;
        f32x2 dt1 = ((Xd[j]*qx1) + (Yd[j]*qy1)) + (Zd[j]*qz1);
        f32x2 tt1 = (C2[j] - dt1) + qw1;
        float e0 = fmaxf(tt0.x, 0.f);
        float e1 = fmaxf(tt0.y, 0.f);
        float e2 = fmaxf(tt1.x, 0.f);
        float e3 = fmaxf(tt1.y, 0.f);
        bool l0 = e0 < best[j]; best[j] = fminf(best[j], e0); code[j] = l0 ? cb       : code[j];
        bool l1 = e1 < best[j]; best[j] = fminf(best[j], e1); code[j] = l1 ? (cb | 1) : code[j];
        bool l2 = e2 < best[j]; best[j] = fminf(best[j], e2); code[j] = l2 ? (cb | 2) : code[j];
        bool l3 = e3 < best[j]; best[j] = fminf(best[j], e3); code[j] = l3 ? (cb | 3) : code[j];
      }
    }
    // tail: partial 32-block (not taken when mlen % 32 == 0)
    int mb0 = nq << 5;
    if (mb0 < mlen) {
      const float* fX = (const float*)sXq; const float* fY = (const float*)sYq;
      const float* fZ = (const float*)sZq; const float* fW = (const float*)sWq;
      #pragma unroll
      for (int e = 0; e < 4; ++e) {
        int m = mb0 + 4*s + e;
        if (m < mlen) {
          float qx = fX[m], qy = fY[m], qz = fZ[m], qw = fW[m];
          int cc = (nq << 2) | e;
          #pragma unroll
          for (int j = 0; j < 4; ++j) {
            float dt2 = ((Xd[j].x*qx) + (Yd[j].x*qy)) + (Zd[j].x*qz);
            float dd = fmaxf((C2[j].x - dt2) + qw, 0.0f);
            bool lt = dd < best[j];
            best[j] = fminf(best[j], dd);
            code[j] = lt ? cc : code[j];
          }
        }
      }
    }
  }

  // merge the 8 slices (butterfly within each 8-lane group), lexicographic
  u64_t pk[4];
  #pragma unroll
  for (int j = 0; j < 4; ++j) {
    int mj = ((code[j] >> 2) << 5) + 4*s + (code[j] & 3);
    pk[j] = ((u64_t)__float_as_uint(best[j]) << 32) | (uint_t)mj;
    u64_t o;
    o = __shfl_xor(pk[j], 1); if (o < pk[j]) pk[j] = o;
    o = __shfl_xor(pk[j], 2); if (o < pk[j]) pk[j] = o;
    o = __shfl_xor(pk[j], 4); if (o < pk[j]) pk[j] = o;
  }

  // lanes s=0..3 each transform one point (no redistribution shuffles)
  if (s < 4) {
    u64_t mypk = (s==0) ? pk[0] : (s==1) ? pk[1] : (s==2) ? pk[2] : pk[3];
    float xa = (s==0) ? X[0] : (s==1) ? X[1] : (s==2) ? X[2] : X[3];
    float ya = (s==0) ? Y[0] : (s==1) ? Y[1] : (s==2) ? Y[2] : Y[3];
    float za = (s==0) ? Z[0] : (s==1) ? Z[1] : (s==2) ? Z[2] : Z[3];
    int n = n0 + s;
    int bm = (int)(mypk & 0xFFFFFFFFull);
    float bd = __uint_as_float((uint_t)(mypk >> 32));
    float pn = sqrtf(bd);
    float fl = ((double)pn < 0.08) ? 1.0f : 0.0f;
    float dxa = pose_dirs[n*3+0], dya = pose_dirs[n*3+1], dza = pose_dirs[n*3+2];
    transform_one(n, p, bm, pn, fl, xa, ya, za, dxa, dya, dza, pbw, sA4, sB4, out);
  }
}

// ---------------- MLP via bf16 MFMA, 16 rows/wave ----------------
// grid: 2560 blocks x 256 threads (4 waves); 64 rows/block, 16 rows/wave.
// (round-5 verified version, unchanged)
__global__ __launch_bounds__(256) void mlp_kernel(
    const float* __restrict__ W1g, const float* __restrict__ b1g,
    const float* __restrict__ b2g, const float* __restrict__ W3g,
    const float* __restrict__ b3g, const ushort_t* __restrict__ W2bf,
    float* __restrict__ out)
{
  __shared__ struct {
    ushort_t B[2][8192];   // double-buffered W2 kc-chunk (16KB each)
    float4   w1c[256];     // {W1[0][c], W1[1][c], W1[2][c], b1[c]}
    float4   w3b2[256];    // {W3[c][0], W3[c][1], W3[c][2], b2[c]}
  } sm;                    // 40960 B exactly -> 4 blocks/CU

  int t = threadIdx.x;
  int wave = t >> 6, lane = t & 63, quad = lane >> 4, m16 = lane & 15;
  size_t row0 = (size_t)blockIdx.x * 64 + (size_t)wave * 16;

  // DMA staging of one 16KB W2 kc-chunk (linear, per-wave 4KB)
  auto stage = [&](int buf, int kc) {
    const ushort_t* src = W2bf + kc*8192 + wave*2048 + lane*8;
    #pragma unroll
    for (int i = 0; i < 4; ++i) {
      __builtin_amdgcn_global_load_lds(
        (const __attribute__((address_space(1))) void*)(src + i*512),
        (__attribute__((address_space(3))) void*)(&sm.B[buf][wave*2048 + i*512]),
        16, 0, 0);
    }
  };
  stage(0, 0);

  {
    int c = t;   // 256 threads exactly
    sm.w1c[c]  = make_float4(W1g[c], W1g[256+c], W1g[512+c], b1g[c]);
    sm.w3b2[c] = make_float4(W3g[c*3+0], W3g[c*3+1], W3g[c*3+2], b2g[c]);
  }

  int r0 = (int)row0 + m16;        // this lane's row
  float x0 = out[O4 + (size_t)r0*3+0], y0 = out[O4 + (size_t)r0*3+1], z0 = out[O4 + (size_t)r0*3+2];

  f32x4 acc0[16];
  #pragma unroll
  for (int nt = 0; nt < 16; ++nt) acc0[nt] = (f32x4){0.f,0.f,0.f,0.f};

  int cur = 0;
  for (int kc = 0; kc < 8; ++kc) {
    asm volatile("s_waitcnt vmcnt(0)" ::: "memory");
    __syncthreads();                      // staged chunk `cur` + params visible
    if (kc < 7) stage(cur ^ 1, kc + 1);   // prefetch next chunk under compute

    // h1 fragment for this lane's row, columns c0..c0+7
    union { bf16x8 v; uint_t u[4]; } ua0;
    int c0 = kc*32 + quad*8;
    #pragma unroll
    for (int jj = 0; jj < 4; ++jj) {
      float4 wA = sm.w1c[c0 + 2*jj];
      float4 wB = sm.w1c[c0 + 2*jj + 1];
      float hA0 = fmaxf(fmaf(z0, wA.z, fmaf(y0, wA.y, fmaf(x0, wA.x, wA.w))), 0.f);
      float hB0 = fmaxf(fmaf(z0, wB.z, fmaf(y0, wB.y, fmaf(x0, wB.x, wB.w))), 0.f);
      ua0.u[jj] = cvt_pk_bf16(hA0, hB0);
    }

    const ushort_t* Bk = &sm.B[cur][lane*8];
    #pragma unroll
    for (int nt = 0; nt < 16; ++nt) {
      bf16x8 Bw = *(const bf16x8*)(Bk + nt*512);
      acc0[nt] = __builtin_amdgcn_mfma_f32_16x16x32_bf16(ua0.v, Bw, acc0[nt], 0, 0, 0);
    }
    cur ^= 1;
  }

  // epilogue: h2[row=quad*4+reg][col=nt*16+m16]; layer-3 f32 + 16-lane reduce.
  float flv = out[O3 + row0 + (size_t)m16];
  float ivx = out[O4 + (row0 + (size_t)m16)*3 + 0];
  float ivy = out[O4 + (row0 + (size_t)m16)*3 + 1];
  float ivz = out[O4 + (row0 + (size_t)m16)*3 + 2];

  float pr[4][3];
  #pragma unroll
  for (int reg = 0; reg < 4; ++reg) { pr[reg][0]=0.f; pr[reg][1]=0.f; pr[reg][2]=0.f; }
  #pragma unroll
  for (int nt = 0; nt < 16; ++nt) {
    float4 cv = sm.w3b2[nt*16 + m16];    // {W3[col], b2[col]}, col=nt*16+m16
    #pragma unroll
    for (int reg = 0; reg < 4; ++reg) {
      float h2 = fmaxf(acc0[nt][reg] + cv.w, 0.f);
      pr[reg][0] = fmaf(h2, cv.x, pr[reg][0]);
      pr[reg][1] = fmaf(h2, cv.y, pr[reg][1]);
      pr[reg][2] = fmaf(h2, cv.z, pr[reg][2]);
    }
  }
  float b30 = b3g[0], b31 = b3g[1], b32 = b3g[2];   // uniform s_loads
  #pragma unroll
  for (int reg = 0; reg < 4; ++reg) {
    float p0 = pr[reg][0], p1 = pr[reg][1], p2 = pr[reg][2];
    #pragma unroll
    for (int mask = 1; mask < 16; mask <<= 1) {
      p0 += __shfl_xor(p0, mask);
      p1 += __shfl_xor(p1, mask);
      p2 += __shfl_xor(p2, mask);
    }
    int src = quad*4 + reg;              // row offset within the wave's 16 rows
    float fl = __shfl(flv, src);
    float i0 = __shfl(ivx, src);
    float i1 = __shfl(ivy, src);
    float i2 = __shfl(ivz, src);
    if (m16 == 0) {
      int r = (int)row0 + src;
      float rr0 = 0.05f * tanh_fast(p0 + b30) * fl;
      float rr1 = 0.05f * tanh_fast(p1 + b31) * fl;
      float rr2 = 0.05f * tanh_fast(p2 + b32) * fl;
      out[O0 + (size_t)r*3+0] = i0 + rr0;
      out[O0 + (size_t)r*3+1] = i1 + rr1;
      out[O0 + (size_t)r*3+2] = i2 + rr2;
      out[O2 + (size_t)r*3+0] = rr0;
      out[O2 + (size_t)r*3+1] = rr1;
      out[O2 + (size_t)r*3+2] = rr2;
    }
  }
}

extern "C" void kernel_launch(void* const* d_in, const int* in_sizes, int n_in,
                              void* d_out, int out_size, void* d_ws, size_t ws_size,
                              hipStream_t stream) {
  (void)out_size; (void)ws_size;
  // size-based slot remap (no-op under documented dict order; protective otherwise)
  const int want[13] = {98304, 98304, 15360, 122880, 384, 384, 768, 256, 65536, 256, 768, 3, 5};
  int idx[13];
  bool used[64] = {false};
  for (int L = 0; L < 13; ++L) {
    idx[L] = -1;
    for (int s = 0; s < n_in && s < 64; ++s) {
      if (!used[s] && in_sizes[s] == want[L]) { idx[L] = s; used[s] = true; break; }
    }
    if (idx[L] < 0) idx[L] = L;
  }
  const float* pp0       = (const float*)d_in[idx[0]];
  const float* pp1       = (const float*)d_in[idx[1]];
  const float* part_pts  = (const float*)d_in[idx[2]];
  const float* part_pbw  = (const float*)d_in[idx[3]];
  const float* A         = (const float*)d_in[idx[4]];
  const float* bigA      = (const float*)d_in[idx[5]];
  const float* W1        = (const float*)d_in[idx[6]];
  const float* b1        = (const float*)d_in[idx[7]];
  const float* W2        = (const float*)d_in[idx[8]];
  const float* b2        = (const float*)d_in[idx[9]];
  const float* W3        = (const float*)d_in[idx[10]];
  const float* b3        = (const float*)d_in[idx[11]];
  const int*   lengths2  = (const int*)d_in[idx[12]];
  float* out = (float*)d_out;
  ushort_t* W2bf = (ushort_t*)d_ws;   // 128 KB of workspace

  nn_kernel<<<1536, 256, 0, stream>>>(pp0, pp1, part_pts, part_pbw,
                                      A, bigA, lengths2, W2, W2bf, out);
  mlp_kernel<<<2560, 256, 0, stream>>>(W1, b1, b2, W3, b3, W2bf, out);
}